// Round 1
// baseline (947.802 us; speedup 1.0000x reference)
//
#include <hip/hip_runtime.h>
#include <hip/hip_bf16.h>
#include <cstdint>
#include <cstddef>

// Problem constants
#define HW   1024   // H*W tokens
#define NC   512    // channels
#define NCO3 1536   // 3*C
#define NB   16     // batch
#define NG   32     // groups
#define EPSV 1e-5f

typedef __hip_bfloat16 bf16;

__device__ __forceinline__ float b2f(bf16 h) { return __bfloat162float(h); }

// ---------------- GroupNorm -> xn (bf16) ----------------
// grid: NB*NG blocks, 256 threads. Each block: 16 ch x 1024 = 16384 floats.
__global__ __launch_bounds__(256) void gn_kernel(
    const float* __restrict__ x, const float* __restrict__ gamma,
    const float* __restrict__ beta, bf16* __restrict__ xn) {
  int blk = blockIdx.x;
  int b = blk >> 5, g = blk & 31;
  size_t base = ((size_t)(b * NC + g * 16)) * HW;
  const float4* src4 = (const float4*)(x + base);
  int t = threadIdx.x;
  float s = 0.f, ss = 0.f;
  float4 v[16];
#pragma unroll
  for (int i = 0; i < 16; ++i) {
    v[i] = src4[t + i * 256];
    s  += v[i].x + v[i].y + v[i].z + v[i].w;
    ss += v[i].x * v[i].x + v[i].y * v[i].y + v[i].z * v[i].z + v[i].w * v[i].w;
  }
  __shared__ float red[256];
  red[t] = s; __syncthreads();
  for (int o = 128; o > 0; o >>= 1) { if (t < o) red[t] += red[t + o]; __syncthreads(); }
  float mean = red[0] * (1.f / 16384.f);
  __syncthreads();
  red[t] = ss; __syncthreads();
  for (int o = 128; o > 0; o >>= 1) { if (t < o) red[t] += red[t + o]; __syncthreads(); }
  float var = red[0] * (1.f / 16384.f) - mean * mean;
  float rstd = rsqrtf(var + EPSV);
  bf16* dst = xn + base;
#pragma unroll
  for (int i = 0; i < 16; ++i) {
    int idx = t + i * 256;            // float4 index in [0,4096)
    int c = g * 16 + (idx >> 8);      // channel of these 4 elements
    float gm = gamma[c], bt = beta[c];
    bf16 h[4];
    h[0] = __float2bfloat16((v[i].x - mean) * rstd * gm + bt);
    h[1] = __float2bfloat16((v[i].y - mean) * rstd * gm + bt);
    h[2] = __float2bfloat16((v[i].z - mean) * rstd * gm + bt);
    h[3] = __float2bfloat16((v[i].w - mean) * rstd * gm + bt);
    *(uint2*)(dst + (size_t)idx * 4) = *(const uint2*)h;
  }
}

// ---------------- QKV GEMM: qkv[b][o][n] = sum_c W[o][c]*xn[b][c][n] + b_in[o]
// grid: (HW/64, NCO3/64, NB), 256 threads, 64x64 tile, 4x4 per thread.
__global__ __launch_bounds__(256) void qkv_kernel(
    const float* __restrict__ w_in, const float* __restrict__ b_in,
    const bf16* __restrict__ xn, bf16* __restrict__ qkv) {
  int b = blockIdx.z;
  int n0 = blockIdx.x * 64;
  int m0 = blockIdx.y * 64;
  const bf16* xb = xn + (size_t)b * NC * HW;
  bf16* qb = qkv + (size_t)b * NCO3 * HW;
  __shared__ float As[16][68];
  __shared__ float Bs[16][68];
  int t = threadIdx.x;
  int tm = t >> 4, tn = t & 15;
  float acc[4][4] = {};
  for (int k0 = 0; k0 < NC; k0 += 16) {
#pragma unroll
    for (int i = 0; i < 4; ++i) {  // A: 64x16 fp32
      int idx = t + i * 256;
      int k = idx & 15, m = idx >> 4;
      As[k][m] = w_in[(size_t)(m0 + m) * NC + k0 + k];
    }
#pragma unroll
    for (int i = 0; i < 4; ++i) {  // B: 16x64 bf16
      int idx = t + i * 256;
      int n = idx & 63, k = idx >> 6;
      Bs[k][n] = b2f(xb[(size_t)(k0 + k) * HW + n0 + n]);
    }
    __syncthreads();
#pragma unroll
    for (int kk = 0; kk < 16; ++kk) {
      float a[4], bb[4];
#pragma unroll
      for (int i = 0; i < 4; ++i) a[i] = As[kk][tm * 4 + i];
#pragma unroll
      for (int j = 0; j < 4; ++j) bb[j] = Bs[kk][tn * 4 + j];
#pragma unroll
      for (int i = 0; i < 4; ++i)
#pragma unroll
        for (int j = 0; j < 4; ++j) acc[i][j] += a[i] * bb[j];
    }
    __syncthreads();
  }
#pragma unroll
  for (int i = 0; i < 4; ++i) {
    int m = m0 + tm * 4 + i;
    float bias = b_in[m];
    bf16 h[4];
#pragma unroll
    for (int j = 0; j < 4; ++j) h[j] = __float2bfloat16(acc[i][j] + bias);
    *(uint2*)(qb + (size_t)m * HW + n0 + tn * 4) = *(const uint2*)h;
  }
}

// ---------------- Scores GEMM: S[i][j] = scale * sum_c q[c][i]*k[c][j]
// grid: (HW/64, HW/64, nb_chunk)
__global__ __launch_bounds__(256) void scores_kernel(
    const bf16* __restrict__ qkv, float* __restrict__ scores, int b_base) {
  int bz = blockIdx.z;
  int b = b_base + bz;
  const bf16* q = qkv + (size_t)b * NCO3 * HW;          // rows 0..511
  const bf16* km = q + (size_t)NC * HW;                 // rows 512..1023
  float* sb = scores + (size_t)bz * HW * HW;
  int j0 = blockIdx.x * 64, i0 = blockIdx.y * 64;
  __shared__ float As[16][68];
  __shared__ float Bs[16][68];
  int t = threadIdx.x;
  int tm = t >> 4, tn = t & 15;
  float acc[4][4] = {};
  for (int c0 = 0; c0 < NC; c0 += 16) {
#pragma unroll
    for (int i = 0; i < 4; ++i) {  // A^T: As[k][m] = q[c0+k][i0+m]
      int idx = t + i * 256;
      int m = idx & 63, k = idx >> 6;
      As[k][m] = b2f(q[(size_t)(c0 + k) * HW + i0 + m]);
    }
#pragma unroll
    for (int i = 0; i < 4; ++i) {
      int idx = t + i * 256;
      int n = idx & 63, k = idx >> 6;
      Bs[k][n] = b2f(km[(size_t)(c0 + k) * HW + j0 + n]);
    }
    __syncthreads();
#pragma unroll
    for (int kk = 0; kk < 16; ++kk) {
      float a[4], bb[4];
#pragma unroll
      for (int i = 0; i < 4; ++i) a[i] = As[kk][tm * 4 + i];
#pragma unroll
      for (int j = 0; j < 4; ++j) bb[j] = Bs[kk][tn * 4 + j];
#pragma unroll
      for (int i = 0; i < 4; ++i)
#pragma unroll
        for (int j = 0; j < 4; ++j) acc[i][j] += a[i] * bb[j];
    }
    __syncthreads();
  }
  const float scale = 0.044194173824159216f;  // 1/sqrt(512)
#pragma unroll
  for (int i = 0; i < 4; ++i) {
    float4 o;
    o.x = acc[i][0] * scale; o.y = acc[i][1] * scale;
    o.z = acc[i][2] * scale; o.w = acc[i][3] * scale;
    *(float4*)(sb + (size_t)(i0 + tm * 4 + i) * HW + j0 + tn * 4) = o;
  }
}

// ---------------- Softmax (fp32 row -> bf16 attn in upper half of same row)
// grid: nb_chunk*1024 blocks, 256 threads (4 elems each).
__global__ __launch_bounds__(256) void softmax_kernel(float* __restrict__ scores) {
  size_t row = blockIdx.x;
  float* srow = scores + row * HW;
  int t = threadIdx.x;
  float4 v = ((const float4*)srow)[t];
  float mx = fmaxf(fmaxf(v.x, v.y), fmaxf(v.z, v.w));
  __shared__ float red[256];
  red[t] = mx; __syncthreads();
  for (int o = 128; o > 0; o >>= 1) { if (t < o) red[t] = fmaxf(red[t], red[t + o]); __syncthreads(); }
  mx = red[0]; __syncthreads();
  float e0 = expf(v.x - mx), e1 = expf(v.y - mx), e2 = expf(v.z - mx), e3 = expf(v.w - mx);
  red[t] = e0 + e1 + e2 + e3; __syncthreads();
  for (int o = 128; o > 0; o >>= 1) { if (t < o) red[t] += red[t + o]; __syncthreads(); }
  float inv = 1.f / red[0];
  // all reads of srow happened before the barriers above; safe to overwrite upper half
  bf16 h[4];
  h[0] = __float2bfloat16(e0 * inv); h[1] = __float2bfloat16(e1 * inv);
  h[2] = __float2bfloat16(e2 * inv); h[3] = __float2bfloat16(e3 * inv);
  bf16* arow = (bf16*)(srow + 512);  // upper 2KB of this row's 4KB
  *(uint2*)(arow + t * 4) = *(const uint2*)h;
}

// ---------------- PV GEMM: ao[b][c][i] = sum_j v[c][j] * attn[i][j]
// grid: (HW/64, NC/64, nb_chunk). attn row i: bf16[1024] at byte i*4096+2048.
__global__ __launch_bounds__(256) void pv_kernel(
    const bf16* __restrict__ qkv, const float* __restrict__ scores,
    bf16* __restrict__ ao, int b_base) {
  int bz = blockIdx.z;
  int b = b_base + bz;
  const bf16* vm = qkv + (size_t)b * NCO3 * HW + (size_t)2 * NC * HW;
  const char* att_base = (const char*)(scores + (size_t)bz * HW * HW);
  int n0 = blockIdx.x * 64, m0 = blockIdx.y * 64;
  __shared__ float As[16][68];
  __shared__ float Bs[16][68];
  int t = threadIdx.x;
  int tm = t >> 4, tn = t & 15;
  float acc[4][4] = {};
  for (int j0 = 0; j0 < HW; j0 += 16) {
#pragma unroll
    for (int i = 0; i < 4; ++i) {  // As[k][m] = v[m0+m][j0+k]
      int idx = t + i * 256;
      int k = idx & 15, m = idx >> 4;
      As[k][m] = b2f(vm[(size_t)(m0 + m) * HW + j0 + k]);
    }
#pragma unroll
    for (int i = 0; i < 4; ++i) {  // Bs[k][n] = attn[n0+n][j0+k]
      int idx = t + i * 256;
      int k = idx & 15, n = idx >> 4;
      const bf16* arow = (const bf16*)(att_base + (size_t)(n0 + n) * 4096 + 2048);
      Bs[k][n] = b2f(arow[j0 + k]);
    }
    __syncthreads();
#pragma unroll
    for (int kk = 0; kk < 16; ++kk) {
      float a[4], bb[4];
#pragma unroll
      for (int i = 0; i < 4; ++i) a[i] = As[kk][tm * 4 + i];
#pragma unroll
      for (int j = 0; j < 4; ++j) bb[j] = Bs[kk][tn * 4 + j];
#pragma unroll
      for (int i = 0; i < 4; ++i)
#pragma unroll
        for (int j = 0; j < 4; ++j) acc[i][j] += a[i] * bb[j];
    }
    __syncthreads();
  }
#pragma unroll
  for (int i = 0; i < 4; ++i) {
    int m = m0 + tm * 4 + i;
    bf16 h[4];
#pragma unroll
    for (int j = 0; j < 4; ++j) h[j] = __float2bfloat16(acc[i][j]);
    *(uint2*)(ao + (size_t)b * NC * HW + (size_t)m * HW + n0 + tn * 4) = *(const uint2*)h;
  }
}

// ---------------- Out GEMM + bias + residual
// grid: (HW/64, NC/64, NB)
__global__ __launch_bounds__(256) void out_kernel(
    const float* __restrict__ w_out, const float* __restrict__ b_out,
    const bf16* __restrict__ ao, const float* __restrict__ x,
    float* __restrict__ out) {
  int b = blockIdx.z;
  int n0 = blockIdx.x * 64;
  int m0 = blockIdx.y * 64;
  const bf16* ab = ao + (size_t)b * NC * HW;
  __shared__ float As[16][68];
  __shared__ float Bs[16][68];
  int t = threadIdx.x;
  int tm = t >> 4, tn = t & 15;
  float acc[4][4] = {};
  for (int k0 = 0; k0 < NC; k0 += 16) {
#pragma unroll
    for (int i = 0; i < 4; ++i) {
      int idx = t + i * 256;
      int k = idx & 15, m = idx >> 4;
      As[k][m] = w_out[(size_t)(m0 + m) * NC + k0 + k];
    }
#pragma unroll
    for (int i = 0; i < 4; ++i) {
      int idx = t + i * 256;
      int n = idx & 63, k = idx >> 6;
      Bs[k][n] = b2f(ab[(size_t)(k0 + k) * HW + n0 + n]);
    }
    __syncthreads();
#pragma unroll
    for (int kk = 0; kk < 16; ++kk) {
      float a[4], bb[4];
#pragma unroll
      for (int i = 0; i < 4; ++i) a[i] = As[kk][tm * 4 + i];
#pragma unroll
      for (int j = 0; j < 4; ++j) bb[j] = Bs[kk][tn * 4 + j];
#pragma unroll
      for (int i = 0; i < 4; ++i)
#pragma unroll
        for (int j = 0; j < 4; ++j) acc[i][j] += a[i] * bb[j];
    }
    __syncthreads();
  }
#pragma unroll
  for (int i = 0; i < 4; ++i) {
    int m = m0 + tm * 4 + i;
    float bias = b_out[m];
    size_t off = (size_t)b * NC * HW + (size_t)m * HW + n0 + tn * 4;
    float4 r = *(const float4*)(x + off);
    float4 o;
    o.x = acc[i][0] + bias + r.x;
    o.y = acc[i][1] + bias + r.y;
    o.z = acc[i][2] + bias + r.z;
    o.w = acc[i][3] + bias + r.w;
    *(float4*)(out + off) = o;
  }
}

extern "C" void kernel_launch(void* const* d_in, const int* in_sizes, int n_in,
                              void* d_out, int out_size, void* d_ws, size_t ws_size,
                              hipStream_t stream) {
  const float* x     = (const float*)d_in[0];
  const float* gamma = (const float*)d_in[1];
  const float* beta  = (const float*)d_in[2];
  const float* w_in  = (const float*)d_in[3];
  const float* b_in  = (const float*)d_in[4];
  const float* w_out = (const float*)d_in[5];
  const float* b_out = (const float*)d_in[6];
  float* out = (float*)d_out;

  char* w = (char*)d_ws;
  bf16* xn  = (bf16*)w;                                   // 16 MB
  bf16* qkv = (bf16*)(w + ((size_t)16 << 20));            // 48 MB
  float* scores = (float*)(w + ((size_t)64 << 20));       // up to 64 MB (chunked)
  bf16* ao = (bf16*)w;                                    // reuse xn region (dead after qkv)

  const size_t slot = (size_t)HW * HW * 4;                // 4 MB per batch of scores
  size_t avail = ws_size > ((size_t)64 << 20) ? ws_size - ((size_t)64 << 20) : slot;
  int chunk = (int)(avail / slot);
  if (chunk > NB) chunk = NB;
  if (chunk < 1) chunk = 1;

  gn_kernel<<<NB * NG, 256, 0, stream>>>(x, gamma, beta, xn);
  qkv_kernel<<<dim3(HW / 64, NCO3 / 64, NB), 256, 0, stream>>>(w_in, b_in, xn, qkv);
  for (int b0 = 0; b0 < NB; b0 += chunk) {
    int nb = NB - b0 < chunk ? NB - b0 : chunk;
    scores_kernel<<<dim3(HW / 64, HW / 64, nb), 256, 0, stream>>>(qkv, scores, b0);
    softmax_kernel<<<nb * HW, 256, 0, stream>>>(scores);
    pv_kernel<<<dim3(HW / 64, NC / 64, nb), 256, 0, stream>>>(qkv, scores, ao, b0);
  }
  out_kernel<<<dim3(HW / 64, NC / 64, NB), 256, 0, stream>>>(w_out, b_out, ao, x, out);
}

// Round 2
// 194.804 us; speedup vs baseline: 4.8654x; 4.8654x over previous
//
#include <hip/hip_runtime.h>
#include <hip/hip_bf16.h>
#include <cstdint>
#include <cstddef>

#define HW   1024   // H*W tokens
#define NC   512    // channels
#define NB   16     // batch
#define EPSV 1e-5f

typedef __hip_bfloat16 bf16;
typedef __attribute__((ext_vector_type(8))) __bf16 bf16x8;
typedef __attribute__((ext_vector_type(4))) float f32x4;

__device__ __forceinline__ float b2f(bf16 h) { return __bfloat162float(h); }

__device__ __forceinline__ void gload16(const void* g, void* l) {
  __builtin_amdgcn_global_load_lds(
      (const __attribute__((address_space(1))) uint32_t*)g,
      (__attribute__((address_space(3))) uint32_t*)l, 16, 0, 0);
}

// ---------------- weight fp32 -> bf16 convert ----------------
// w_in: 1536*512 = 196608 float4; w_out: 512*512 = 65536 float4. 1024 blocks.
__global__ __launch_bounds__(256) void cvt_w_kernel(
    const float* __restrict__ wi, const float* __restrict__ wo,
    bf16* __restrict__ wib, bf16* __restrict__ wob) {
  int i = blockIdx.x * 256 + threadIdx.x;
  const float4* src;
  bf16* dst;
  int j;
  if (i < 196608) { src = (const float4*)wi; j = i; dst = wib; }
  else            { src = (const float4*)wo; j = i - 196608; dst = wob; }
  float4 v = src[j];
  union { bf16 h[4]; uint2 u; } p;
  p.h[0] = __float2bfloat16(v.x); p.h[1] = __float2bfloat16(v.y);
  p.h[2] = __float2bfloat16(v.z); p.h[3] = __float2bfloat16(v.w);
  *(uint2*)&dst[(size_t)j * 4] = p.u;
}

// ---------------- GroupNorm -> xn token-major bf16 [b][hw][c] ----------------
// grid: NB*32 blocks (one per (batch,group)), 256 threads.
__global__ __launch_bounds__(256) void gn_kernel(
    const float* __restrict__ x, const float* __restrict__ gamma,
    const float* __restrict__ beta, bf16* __restrict__ xn) {
  int blk = blockIdx.x;
  int b = blk >> 5, g = blk & 31;
  size_t base = ((size_t)(b * NC + g * 16)) * HW;
  const float4* src4 = (const float4*)(x + base);
  int t = threadIdx.x;
  float s = 0.f, ss = 0.f;
  float4 v[16];
#pragma unroll
  for (int i = 0; i < 16; ++i) {
    v[i] = src4[t + i * 256];
    s  += v[i].x + v[i].y + v[i].z + v[i].w;
    ss += v[i].x * v[i].x + v[i].y * v[i].y + v[i].z * v[i].z + v[i].w * v[i].w;
  }
  __shared__ float red[256];
  red[t] = s; __syncthreads();
  for (int o = 128; o > 0; o >>= 1) { if (t < o) red[t] += red[t + o]; __syncthreads(); }
  float mean = red[0] * (1.f / 16384.f);
  __syncthreads();
  red[t] = ss; __syncthreads();
  for (int o = 128; o > 0; o >>= 1) { if (t < o) red[t] += red[t + o]; __syncthreads(); }
  float var = red[0] * (1.f / 16384.f) - mean * mean;
  float rstd = rsqrtf(var + EPSV);

  // normalized -> LDS [16 ch][1032 hw] (padded to dodge bank conflicts)
  __shared__ bf16 sm[16][1032];
#pragma unroll
  for (int i = 0; i < 16; ++i) {
    int idx = t + i * 256;
    int c = idx >> 8;              // 0..15
    int hw4 = (idx & 255) * 4;
    float gm = gamma[g * 16 + c], bt = beta[g * 16 + c];
    union { bf16 h[4]; uint2 u; } p;
    p.h[0] = __float2bfloat16((v[i].x - mean) * rstd * gm + bt);
    p.h[1] = __float2bfloat16((v[i].y - mean) * rstd * gm + bt);
    p.h[2] = __float2bfloat16((v[i].z - mean) * rstd * gm + bt);
    p.h[3] = __float2bfloat16((v[i].w - mean) * rstd * gm + bt);
    *(uint2*)&sm[c][hw4] = p.u;
  }
  __syncthreads();
  // write token-major: xn[b][hw][512], this block owns c in [g*16, g*16+16)
  bf16* dst = xn + (size_t)b * HW * NC + g * 16;
#pragma unroll
  for (int it = 0; it < 8; ++it) {
    int u = it * 256 + t;          // 0..2047
    int hw = u >> 1;
    int c8 = (u & 1) * 8;
    union { bf16 h[8]; uint4 q; } p;
#pragma unroll
    for (int j = 0; j < 8; ++j) p.h[j] = sm[c8 + j][hw];
    *(uint4*)&dst[(size_t)hw * NC + c8] = p.q;
  }
}

// ---------------- universal MFMA GEMM: C[M][N] = A[M][K] * B^T[N][K] --------
// 128x128 tile, 4 waves (2x2 of 64x64), BK=32, mfma_f32_16x16x32_bf16.
// grid: (N/128, M/128, nbatch). Both A and B are K-contiguous bf16.
// MODE 0: bf16 store transposed  C[col*ldc+row], bias[row]        (qk proj)
// MODE 1: bf16 store row-major   C[row*ldc+col], optional bias    (v proj, pv)
// MODE 2: f32  store row-major, * scale                           (scores)
// MODE 3: f32  store row-major, + bias[row] + resid               (out proj)
template <int MODE>
__global__ __launch_bounds__(256) void gemm_bt(
    const bf16* __restrict__ A, int lda, long long sA,
    const bf16* __restrict__ B, int ldb, long long sB,
    void* __restrict__ Cv, int ldc, long long sC,
    int K,
    const float* __restrict__ bias,
    const float* __restrict__ resid, long long sR,
    float scale) {
  __shared__ bf16 sT[2][128][32];   // [0]=A tile, [1]=B tile
  int z = blockIdx.z;
  const bf16* Ab = A + (size_t)z * sA;
  const bf16* Bb = B + (size_t)z * sB;
  int n0 = blockIdx.x * 128, m0 = blockIdx.y * 128;
  int t = threadIdx.x;
  int l = t & 63, w = t >> 6;
  int wm = w >> 1, wn = w & 1;

  int srow = t >> 2;            // 0..63 staging row
  int scol = (t & 3) * 8;       // bf16 col chunk

  f32x4 acc[4][4] = {};

  const bf16* ga0 = Ab + (size_t)(m0 + srow) * lda + scol;
  const bf16* gb0 = Bb + (size_t)(n0 + srow) * ldb + scol;

  for (int k0 = 0; k0 < K; k0 += 32) {
    gload16(ga0 + k0, &sT[0][srow][scol]);
    gload16(ga0 + (size_t)64 * lda + k0, &sT[0][64 + srow][scol]);
    gload16(gb0 + k0, &sT[1][srow][scol]);
    gload16(gb0 + (size_t)64 * ldb + k0, &sT[1][64 + srow][scol]);
    __syncthreads();
    bf16x8 af[4], bfr[4];
    int kc = (l >> 4) * 8;
    int ra = wm * 64 + (l & 15);
    int rb = wn * 64 + (l & 15);
#pragma unroll
    for (int i = 0; i < 4; ++i) {
      af[i]  = *(const bf16x8*)&sT[0][ra + i * 16][kc];
      bfr[i] = *(const bf16x8*)&sT[1][rb + i * 16][kc];
    }
#pragma unroll
    for (int i = 0; i < 4; ++i)
#pragma unroll
      for (int j = 0; j < 4; ++j)
        acc[i][j] = __builtin_amdgcn_mfma_f32_16x16x32_bf16(af[i], bfr[j], acc[i][j], 0, 0, 0);
    __syncthreads();
  }

  int rbase = (l >> 4) * 4;
#pragma unroll
  for (int i = 0; i < 4; ++i) {
    int row = m0 + wm * 64 + i * 16 + rbase;   // M index (rows row..row+3)
    float4 bv = make_float4(0.f, 0.f, 0.f, 0.f);
    if (MODE == 0 || MODE == 3) bv = *(const float4*)&bias[row];
    else if (MODE == 1) { if (bias) bv = *(const float4*)&bias[row]; }
#pragma unroll
    for (int j = 0; j < 4; ++j) {
      int col = n0 + wn * 64 + j * 16 + (l & 15);  // N index
      if (MODE == 0) {
        bf16* C = (bf16*)Cv + (size_t)z * sC;
        union { bf16 h[4]; uint2 u; } p;
        p.h[0] = __float2bfloat16(acc[i][j][0] + bv.x);
        p.h[1] = __float2bfloat16(acc[i][j][1] + bv.y);
        p.h[2] = __float2bfloat16(acc[i][j][2] + bv.z);
        p.h[3] = __float2bfloat16(acc[i][j][3] + bv.w);
        *(uint2*)&C[(size_t)col * ldc + row] = p.u;
      } else if (MODE == 1) {
        bf16* C = (bf16*)Cv + (size_t)z * sC;
        float bb[4] = {bv.x, bv.y, bv.z, bv.w};
#pragma unroll
        for (int r = 0; r < 4; ++r)
          C[(size_t)(row + r) * ldc + col] = __float2bfloat16(acc[i][j][r] + bb[r]);
      } else if (MODE == 2) {
        float* C = (float*)Cv + (size_t)z * sC;
#pragma unroll
        for (int r = 0; r < 4; ++r)
          C[(size_t)(row + r) * ldc + col] = acc[i][j][r] * scale;
      } else {
        float* C = (float*)Cv + (size_t)z * sC;
        float bb[4] = {bv.x, bv.y, bv.z, bv.w};
#pragma unroll
        for (int r = 0; r < 4; ++r) {
          size_t off = (size_t)(row + r) * ldc + col;
          C[off] = acc[i][j][r] + bb[r] + resid[(size_t)z * sR + off];
        }
      }
    }
  }
}

// ---------------- Softmax (fp32 row -> bf16 attn in upper half of same row)
__global__ __launch_bounds__(256) void softmax_kernel(float* __restrict__ scores) {
  size_t row = blockIdx.x;
  float* srow = scores + row * HW;
  int t = threadIdx.x;
  float4 v = ((const float4*)srow)[t];
  float mx = fmaxf(fmaxf(v.x, v.y), fmaxf(v.z, v.w));
  __shared__ float red[256];
  red[t] = mx; __syncthreads();
  for (int o = 128; o > 0; o >>= 1) { if (t < o) red[t] = fmaxf(red[t], red[t + o]); __syncthreads(); }
  mx = red[0]; __syncthreads();
  float e0 = expf(v.x - mx), e1 = expf(v.y - mx), e2 = expf(v.z - mx), e3 = expf(v.w - mx);
  red[t] = e0 + e1 + e2 + e3; __syncthreads();
  for (int o = 128; o > 0; o >>= 1) { if (t < o) red[t] += red[t + o]; __syncthreads(); }
  float inv = 1.f / red[0];
  union { bf16 h[4]; uint2 u; } p;
  p.h[0] = __float2bfloat16(e0 * inv); p.h[1] = __float2bfloat16(e1 * inv);
  p.h[2] = __float2bfloat16(e2 * inv); p.h[3] = __float2bfloat16(e3 * inv);
  bf16* arow = (bf16*)(srow + 512);
  *(uint2*)&arow[t * 4] = p.u;
}

extern "C" void kernel_launch(void* const* d_in, const int* in_sizes, int n_in,
                              void* d_out, int out_size, void* d_ws, size_t ws_size,
                              hipStream_t stream) {
  const float* x     = (const float*)d_in[0];
  const float* gamma = (const float*)d_in[1];
  const float* beta  = (const float*)d_in[2];
  const float* w_in  = (const float*)d_in[3];
  const float* b_in  = (const float*)d_in[4];
  const float* w_out = (const float*)d_in[5];
  const float* b_out = (const float*)d_in[6];
  float* out = (float*)d_out;

  char* w = (char*)d_ws;
  bf16* xn  = (bf16*)w;                              // 16 MB, token-major [b][hw][c]
  bf16* ao  = xn;                                    // reuse after qk/v GEMMs
  bf16* qk  = (bf16*)(w + ((size_t)16 << 20));       // 32 MB, [b][token][1024] (q|k)
  bf16* vcm = (bf16*)(w + ((size_t)48 << 20));       // 16 MB, [b][c][token]
  bf16* wib = (bf16*)(w + ((size_t)64 << 20));       // 1.5 MB
  bf16* wob = (bf16*)(w + ((size_t)64 << 20) + ((size_t)3 << 19));  // 0.5 MB
  float* scores = (float*)(w + ((size_t)66 << 20));  // chunk * 4 MB

  const size_t slot = (size_t)HW * HW * 4;
  size_t avail = ws_size > ((size_t)66 << 20) ? ws_size - ((size_t)66 << 20) : 0;
  int chunk = (int)(avail / slot);
  if (chunk > NB) chunk = NB;
  if (chunk < 1) chunk = 1;

  cvt_w_kernel<<<1024, 256, 0, stream>>>(w_in, w_out, wib, wob);
  gn_kernel<<<NB * 32, 256, 0, stream>>>(x, gamma, beta, xn);

  // QK proj: M=1024 (o: q|k), N=1024 (token), K=512 -> qk[b][token][o] (transposed store)
  gemm_bt<0><<<dim3(8, 8, NB), 256, 0, stream>>>(
      wib, 512, 0, xn, 512, 512 * 1024, qk, 1024, 1024 * 1024, 512,
      b_in, nullptr, 0, 0.f);
  // V proj: M=512 (c), N=1024 (token), K=512 -> vcm[b][c][token]
  gemm_bt<1><<<dim3(8, 4, NB), 256, 0, stream>>>(
      wib + 1024 * 512, 512, 0, xn, 512, 512 * 1024, vcm, 1024, 512 * 1024, 512,
      b_in + 1024, nullptr, 0, 0.f);

  const float scl = 0.044194173824159216f;  // 1/sqrt(512)
  for (int b0 = 0; b0 < NB; b0 += chunk) {
    int nb = NB - b0 < chunk ? NB - b0 : chunk;
    // scores: M=1024 (i), N=1024 (j), K=512
    gemm_bt<2><<<dim3(8, 8, nb), 256, 0, stream>>>(
        qk + (size_t)b0 * 1048576, 1024, 1048576,
        qk + (size_t)b0 * 1048576 + 512, 1024, 1048576,
        scores, 1024, 1048576, 512, nullptr, nullptr, 0, scl);
    softmax_kernel<<<nb * 1024, 256, 0, stream>>>(scores);
    // PV: M=1024 (i), N=512 (c), K=1024 (j); A=attn (upper half of score rows)
    gemm_bt<1><<<dim3(4, 8, nb), 256, 0, stream>>>(
        (bf16*)scores + 1024, 2048, 2097152,
        vcm + (size_t)b0 * 524288, 1024, 524288,
        ao + (size_t)b0 * 524288, 512, 524288, 1024,
        nullptr, nullptr, 0, 0.f);
  }
  // out proj: M=512 (c), N=1024 (i), K=512 -> out[b][c][i] + bias + residual
  gemm_bt<3><<<dim3(8, 4, NB), 256, 0, stream>>>(
      wob, 512, 0, ao, 512, 524288, out, 1024, 524288, 512,
      b_out, x, 524288, 0.f);
}

// Round 3
// 172.962 us; speedup vs baseline: 5.4798x; 1.1263x over previous
//
#include <hip/hip_runtime.h>
#include <hip/hip_bf16.h>
#include <cstdint>
#include <cstddef>

#define HW   1024   // H*W tokens
#define NC   512    // channels
#define NB   16     // batch
#define EPSV 1e-5f

typedef __hip_bfloat16 bf16;
typedef __attribute__((ext_vector_type(8))) __bf16 bf16x8;
typedef __attribute__((ext_vector_type(4))) float f32x4;

__device__ __forceinline__ float b2f(bf16 h) { return __bfloat162float(h); }

__device__ __forceinline__ void gload16(const void* g, void* l) {
  __builtin_amdgcn_global_load_lds(
      (const __attribute__((address_space(1))) uint32_t*)g,
      (__attribute__((address_space(3))) uint32_t*)l, 16, 0, 0);
}

// ---------------- weight fp32 -> bf16 convert ----------------
__global__ __launch_bounds__(256) void cvt_w_kernel(
    const float* __restrict__ wi, const float* __restrict__ wo,
    bf16* __restrict__ wib, bf16* __restrict__ wob) {
  int i = blockIdx.x * 256 + threadIdx.x;
  const float4* src;
  bf16* dst;
  int j;
  if (i < 196608) { src = (const float4*)wi; j = i; dst = wib; }
  else            { src = (const float4*)wo; j = i - 196608; dst = wob; }
  float4 v = src[j];
  union { bf16 h[4]; uint2 u; } p;
  p.h[0] = __float2bfloat16(v.x); p.h[1] = __float2bfloat16(v.y);
  p.h[2] = __float2bfloat16(v.z); p.h[3] = __float2bfloat16(v.w);
  *(uint2*)&dst[(size_t)j * 4] = p.u;
}

// ---------------- GroupNorm -> xn token-major bf16 [b][hw][c] ----------------
__global__ __launch_bounds__(256) void gn_kernel(
    const float* __restrict__ x, const float* __restrict__ gamma,
    const float* __restrict__ beta, bf16* __restrict__ xn) {
  int blk = blockIdx.x;
  int b = blk >> 5, g = blk & 31;
  size_t base = ((size_t)(b * NC + g * 16)) * HW;
  const float4* src4 = (const float4*)(x + base);
  int t = threadIdx.x;
  float s = 0.f, ss = 0.f;
  float4 v[16];
#pragma unroll
  for (int i = 0; i < 16; ++i) {
    v[i] = src4[t + i * 256];
    s  += v[i].x + v[i].y + v[i].z + v[i].w;
    ss += v[i].x * v[i].x + v[i].y * v[i].y + v[i].z * v[i].z + v[i].w * v[i].w;
  }
  __shared__ float red[256];
  red[t] = s; __syncthreads();
  for (int o = 128; o > 0; o >>= 1) { if (t < o) red[t] += red[t + o]; __syncthreads(); }
  float mean = red[0] * (1.f / 16384.f);
  __syncthreads();
  red[t] = ss; __syncthreads();
  for (int o = 128; o > 0; o >>= 1) { if (t < o) red[t] += red[t + o]; __syncthreads(); }
  float var = red[0] * (1.f / 16384.f) - mean * mean;
  float rstd = rsqrtf(var + EPSV);

  __shared__ bf16 sm[16][1032];
#pragma unroll
  for (int i = 0; i < 16; ++i) {
    int idx = t + i * 256;
    int c = idx >> 8;
    int hw4 = (idx & 255) * 4;
    float gm = gamma[g * 16 + c], bt = beta[g * 16 + c];
    union { bf16 h[4]; uint2 u; } p;
    p.h[0] = __float2bfloat16((v[i].x - mean) * rstd * gm + bt);
    p.h[1] = __float2bfloat16((v[i].y - mean) * rstd * gm + bt);
    p.h[2] = __float2bfloat16((v[i].z - mean) * rstd * gm + bt);
    p.h[3] = __float2bfloat16((v[i].w - mean) * rstd * gm + bt);
    *(uint2*)&sm[c][hw4] = p.u;
  }
  __syncthreads();
  bf16* dst = xn + (size_t)b * HW * NC + g * 16;
#pragma unroll
  for (int it = 0; it < 8; ++it) {
    int u = it * 256 + t;
    int hw = u >> 1;
    int c8 = (u & 1) * 8;
    union { bf16 h[8]; uint4 q; } p;
#pragma unroll
    for (int j = 0; j < 8; ++j) p.h[j] = sm[c8 + j][hw];
    *(uint4*)&dst[(size_t)hw * NC + c8] = p.q;
  }
}

// ---------------- universal MFMA GEMM: C[M][N] = A[M][K] * B^T[N][K] --------
// MODE 0: bf16 store transposed  C[col*ldc+row], bias[row]        (qk proj)
// MODE 1: bf16 store row-major   C[row*ldc+col], optional bias    (v proj)
// MODE 3: f32  store row-major, + bias[row] + resid               (out proj)
template <int MODE>
__global__ __launch_bounds__(256) void gemm_bt(
    const bf16* __restrict__ A, int lda, long long sA,
    const bf16* __restrict__ B, int ldb, long long sB,
    void* __restrict__ Cv, int ldc, long long sC,
    int K,
    const float* __restrict__ bias,
    const float* __restrict__ resid, long long sR,
    float scale) {
  __shared__ bf16 sT[2][128][32];
  int z = blockIdx.z;
  const bf16* Ab = A + (size_t)z * sA;
  const bf16* Bb = B + (size_t)z * sB;
  int n0 = blockIdx.x * 128, m0 = blockIdx.y * 128;
  int t = threadIdx.x;
  int l = t & 63, w = t >> 6;
  int wm = w >> 1, wn = w & 1;

  int srow = t >> 2;
  int scol = (t & 3) * 8;

  f32x4 acc[4][4] = {};

  const bf16* ga0 = Ab + (size_t)(m0 + srow) * lda + scol;
  const bf16* gb0 = Bb + (size_t)(n0 + srow) * ldb + scol;

  for (int k0 = 0; k0 < K; k0 += 32) {
    gload16(ga0 + k0, &sT[0][srow][scol]);
    gload16(ga0 + (size_t)64 * lda + k0, &sT[0][64 + srow][scol]);
    gload16(gb0 + k0, &sT[1][srow][scol]);
    gload16(gb0 + (size_t)64 * ldb + k0, &sT[1][64 + srow][scol]);
    __syncthreads();
    bf16x8 af[4], bfr[4];
    int kc = (l >> 4) * 8;
    int ra = wm * 64 + (l & 15);
    int rb = wn * 64 + (l & 15);
#pragma unroll
    for (int i = 0; i < 4; ++i) {
      af[i]  = *(const bf16x8*)&sT[0][ra + i * 16][kc];
      bfr[i] = *(const bf16x8*)&sT[1][rb + i * 16][kc];
    }
#pragma unroll
    for (int i = 0; i < 4; ++i)
#pragma unroll
      for (int j = 0; j < 4; ++j)
        acc[i][j] = __builtin_amdgcn_mfma_f32_16x16x32_bf16(af[i], bfr[j], acc[i][j], 0, 0, 0);
    __syncthreads();
  }

  int rbase = (l >> 4) * 4;
#pragma unroll
  for (int i = 0; i < 4; ++i) {
    int row = m0 + wm * 64 + i * 16 + rbase;
    float4 bv = make_float4(0.f, 0.f, 0.f, 0.f);
    if (MODE == 0 || MODE == 3) bv = *(const float4*)&bias[row];
    else if (MODE == 1) { if (bias) bv = *(const float4*)&bias[row]; }
#pragma unroll
    for (int j = 0; j < 4; ++j) {
      int col = n0 + wn * 64 + j * 16 + (l & 15);
      if (MODE == 0) {
        bf16* C = (bf16*)Cv + (size_t)z * sC;
        union { bf16 h[4]; uint2 u; } p;
        p.h[0] = __float2bfloat16(acc[i][j][0] + bv.x);
        p.h[1] = __float2bfloat16(acc[i][j][1] + bv.y);
        p.h[2] = __float2bfloat16(acc[i][j][2] + bv.z);
        p.h[3] = __float2bfloat16(acc[i][j][3] + bv.w);
        *(uint2*)&C[(size_t)col * ldc + row] = p.u;
      } else if (MODE == 1) {
        bf16* C = (bf16*)Cv + (size_t)z * sC;
        float bb[4] = {bv.x, bv.y, bv.z, bv.w};
#pragma unroll
        for (int r = 0; r < 4; ++r)
          C[(size_t)(row + r) * ldc + col] = __float2bfloat16(acc[i][j][r] + bb[r]);
      } else {
        float* C = (float*)Cv + (size_t)z * sC;
        float bb[4] = {bv.x, bv.y, bv.z, bv.w};
#pragma unroll
        for (int r = 0; r < 4; ++r) {
          size_t off = (size_t)(row + r) * ldc + col;
          C[off] = acc[i][j][r] + bb[r] + resid[(size_t)z * sR + off];
        }
      }
    }
  }
}

// ---------------- fused flash attention ----------------
// grid: 256 wg (XCD-swizzled (qtile, batch)), 512 threads (8 waves).
// Q-tile 64 rows in swizzled LDS; K,V gathered from global (L2-resident);
// S^T via mfma(K,Q) -> online softmax lane-local; P in swizzled LDS;
// O^T via mfma(V,P), wave owns 64-channel slice; final /l, store bf16.
__global__ __launch_bounds__(512, 2) void flash_kernel(
    const bf16* __restrict__ qk, const bf16* __restrict__ vcm,
    bf16* __restrict__ ao) {
  __shared__ bf16 Qs[64 * 512];       // 64KB, swizzled: byte (i*1024+ch*2)^((i&7)<<4)
  __shared__ bf16 Ps[64 * 128];       // 16KB, swizzled: byte (i*256+j*2)^((i&7)<<4)
  __shared__ float redm[8][64];
  __shared__ float redl[8][64];
  __shared__ float lg[64];

  int id = blockIdx.x;
  int xcd = id & 7, rest = id >> 3;
  int q = rest & 15, bh = rest >> 4;
  int b = xcd + bh * 8;               // batch -> fixed XCD (K/V L2 locality)
  int i0 = q * 64;

  const bf16* qkb = qk + (size_t)b * (HW * 1024);
  const bf16* vb  = vcm + (size_t)b * (NC * HW);
  bf16* aob = ao + (size_t)b * (HW * NC) + (size_t)i0 * NC;

  int t = threadIdx.x;
  int l = t & 63, w = t >> 6;
  int l15 = l & 15, lq = l >> 4;

  // stage Q (rows i0..i0+63, q-half cols 0..511) with pre-swizzled source
  {
    const char* qrow_base = (const char*)qkb + (size_t)i0 * 2048;
#pragma unroll
    for (int it = 0; it < 8; ++it) {
      int s = it * 8192 + t * 16;
      int i = s >> 10;
      int wb = s & 1023;
      const char* src = qrow_base + (size_t)i * 2048 + (wb ^ ((i & 7) << 4));
      gload16(src, ((char*)Qs) + s);
    }
  }
  if (w == 0) lg[l] = 0.f;
  float m_prev[4] = {-1e30f, -1e30f, -1e30f, -1e30f};
  f32x4 o[4][4] = {};                  // [mi: ch frag][ni: i frag]
  const float scl = 0.044194173824159216f;   // 1/sqrt(512)

  __syncthreads();   // B0: Q staged (barrier drains vmcnt), lg init

  for (int tile = 0; tile < 8; ++tile) {
    int jb = tile * 128 + w * 16;      // this wave's 16 K-rows
    // ---- QK^T: S^T[16 j][64 i], K gathered, Q from LDS
    f32x4 s[4] = {};
    const bf16* kp = qkb + (size_t)(jb + l15) * 1024 + 512 + lq * 8;
#pragma unroll
    for (int ks = 0; ks < 16; ++ks) {
      bf16x8 kf = *(const bf16x8*)(kp + ks * 32);
#pragma unroll
      for (int bi = 0; bi < 4; ++bi) {
        int i = bi * 16 + l15;
        int off = (i * 1024 + ks * 64 + lq * 16) ^ ((i & 7) << 4);
        bf16x8 qf = *(const bf16x8*)(((const char*)Qs) + off);
        s[bi] = __builtin_amdgcn_mfma_f32_16x16x32_bf16(kf, qf, s[bi], 0, 0, 0);
      }
    }
    // ---- per-row tile max (scaled domain)
    float tm[4];
#pragma unroll
    for (int bi = 0; bi < 4; ++bi) {
      float v = fmaxf(fmaxf(s[bi][0], s[bi][1]), fmaxf(s[bi][2], s[bi][3]));
      v = fmaxf(v, __shfl_xor(v, 16));
      v = fmaxf(v, __shfl_xor(v, 32));
      tm[bi] = v * scl;
    }
    if (l < 16) {
#pragma unroll
      for (int bi = 0; bi < 4; ++bi) redm[w][bi * 16 + l] = tm[bi];
    }
    __syncthreads();  // B1: redm ready; prev-tile Ps reads done
    float mnew[4], sc[4], psum[4];
#pragma unroll
    for (int bi = 0; bi < 4; ++bi) {
      int row = bi * 16 + l15;
      float v = redm[0][row];
#pragma unroll
      for (int w2 = 1; w2 < 8; ++w2) v = fmaxf(v, redm[w2][row]);
      mnew[bi] = fmaxf(m_prev[bi], v);
      sc[bi] = __expf(m_prev[bi] - mnew[bi]);
      float p0 = __expf(s[bi][0] * scl - mnew[bi]);
      float p1 = __expf(s[bi][1] * scl - mnew[bi]);
      float p2 = __expf(s[bi][2] * scl - mnew[bi]);
      float p3 = __expf(s[bi][3] * scl - mnew[bi]);
      psum[bi] = p0 + p1 + p2 + p3;
      union { bf16 h[4]; uint64_t u; } pk;
      pk.h[0] = __float2bfloat16(p0); pk.h[1] = __float2bfloat16(p1);
      pk.h[2] = __float2bfloat16(p2); pk.h[3] = __float2bfloat16(p3);
      int jl = w * 16 + lq * 4;
      int off = (row * 256 + jl * 2) ^ ((row & 7) << 4);
      *(uint64_t*)(((char*)Ps) + off) = pk.u;
      m_prev[bi] = mnew[bi];
    }
#pragma unroll
    for (int bi = 0; bi < 4; ++bi) {
      float v = psum[bi];
      v += __shfl_xor(v, 16);
      v += __shfl_xor(v, 32);
      psum[bi] = v;
    }
    if (l < 16) {
#pragma unroll
      for (int bi = 0; bi < 4; ++bi) redl[w][bi * 16 + l] = psum[bi];
    }
    __syncthreads();  // B2: redl + Ps ready
    if (w == 0 && l < 16) {
#pragma unroll
      for (int bi = 0; bi < 4; ++bi) {
        int row = bi * 16 + l;
        float v = redl[0][row];
#pragma unroll
        for (int w2 = 1; w2 < 8; ++w2) v += redl[w2][row];
        lg[row] = lg[row] * sc[bi] + v;
      }
    }
    // rescale O (factor depends on i-frag ni only -> lane-local)
#pragma unroll
    for (int mi = 0; mi < 4; ++mi)
#pragma unroll
      for (int ni = 0; ni < 4; ++ni) {
        o[mi][ni][0] *= sc[ni]; o[mi][ni][1] *= sc[ni];
        o[mi][ni][2] *= sc[ni]; o[mi][ni][3] *= sc[ni];
      }
    // ---- PV: O^T[64 ch slice][64 i] += V^T x P
    int chb = w * 64;
#pragma unroll
    for (int ks = 0; ks < 4; ++ks) {
      int j0 = tile * 128 + ks * 32;
      bf16x8 vf[4];
#pragma unroll
      for (int mi = 0; mi < 4; ++mi)
        vf[mi] = *(const bf16x8*)(vb + (size_t)(chb + mi * 16 + l15) * 1024 + j0 + lq * 8);
#pragma unroll
      for (int ni = 0; ni < 4; ++ni) {
        int i = ni * 16 + l15;
        int off = (i * 256 + (ks * 32 + lq * 8) * 2) ^ ((i & 7) << 4);
        bf16x8 pf = *(const bf16x8*)(((const char*)Ps) + off);
#pragma unroll
        for (int mi = 0; mi < 4; ++mi)
          o[mi][ni] = __builtin_amdgcn_mfma_f32_16x16x32_bf16(vf[mi], pf, o[mi][ni], 0, 0, 0);
      }
    }
  }
  __syncthreads();  // B3: lg final
  float linv[4];
#pragma unroll
  for (int ni = 0; ni < 4; ++ni) linv[ni] = 1.f / lg[ni * 16 + l15];
  int chb = w * 64;
#pragma unroll
  for (int mi = 0; mi < 4; ++mi)
#pragma unroll
    for (int ni = 0; ni < 4; ++ni) {
      union { bf16 h[4]; uint64_t u; } pk;
#pragma unroll
      for (int r = 0; r < 4; ++r)
        pk.h[r] = __float2bfloat16(o[mi][ni][r] * linv[ni]);
      int i = ni * 16 + l15;
      int ch = chb + mi * 16 + lq * 4;
      *(uint64_t*)(aob + (size_t)i * NC + ch) = pk.u;
    }
}

extern "C" void kernel_launch(void* const* d_in, const int* in_sizes, int n_in,
                              void* d_out, int out_size, void* d_ws, size_t ws_size,
                              hipStream_t stream) {
  const float* x     = (const float*)d_in[0];
  const float* gamma = (const float*)d_in[1];
  const float* beta  = (const float*)d_in[2];
  const float* w_in  = (const float*)d_in[3];
  const float* b_in  = (const float*)d_in[4];
  const float* w_out = (const float*)d_in[5];
  const float* b_out = (const float*)d_in[6];
  float* out = (float*)d_out;

  char* w = (char*)d_ws;
  bf16* xn  = (bf16*)w;                              // 16 MB, token-major [b][hw][c]
  bf16* ao  = xn;                                    // reuse after projections
  bf16* qk  = (bf16*)(w + ((size_t)16 << 20));       // 32 MB, [b][token][1024] (q|k)
  bf16* vcm = (bf16*)(w + ((size_t)48 << 20));       // 16 MB, [b][c][token]
  bf16* wib = (bf16*)(w + ((size_t)64 << 20));       // 1.5 MB
  bf16* wob = (bf16*)(w + ((size_t)64 << 20) + ((size_t)3 << 19));  // 0.5 MB

  cvt_w_kernel<<<1024, 256, 0, stream>>>(w_in, w_out, wib, wob);
  gn_kernel<<<NB * 32, 256, 0, stream>>>(x, gamma, beta, xn);

  // QK proj: M=1024 (o: q|k), N=1024 (token), K=512 -> qk[b][token][o]
  gemm_bt<0><<<dim3(8, 8, NB), 256, 0, stream>>>(
      wib, 512, 0, xn, 512, 512 * 1024, qk, 1024, 1024 * 1024, 512,
      b_in, nullptr, 0, 0.f);
  // V proj: M=512 (c), N=1024 (token), K=512 -> vcm[b][c][token]
  gemm_bt<1><<<dim3(8, 4, NB), 256, 0, stream>>>(
      wib + 1024 * 512, 512, 0, xn, 512, 512 * 1024, vcm, 1024, 512 * 1024, 512,
      b_in + 1024, nullptr, 0, 0.f);

  // fused attention: scores + softmax + PV
  flash_kernel<<<256, 512, 0, stream>>>(qk, vcm, ao);

  // out proj: M=512 (c), N=1024 (i), K=512 -> out[b][c][i] + bias + residual
  gemm_bt<3><<<dim3(8, 4, NB), 256, 0, stream>>>(
      wob, 512, 0, ao, 512, 524288, out, 1024, 524288, 512,
      b_out, x, 524288, 0.f);
}